// Round 9
// baseline (2104.183 us; speedup 1.0000x reference)
//
#include <hip/hip_runtime.h>
#include <cstdint>

#define HIDDEN  128
#define NLAYERS 6
#define NNODES  50000
#define NEDGES  640000

typedef short short8 __attribute__((ext_vector_type(8)));
typedef float f32x4  __attribute__((ext_vector_type(4)));

// ---- bf16 <-> f32 helpers (RNE) -------------------------------------------
__device__ __forceinline__ float bf2f(unsigned short u) {
    return __uint_as_float(((unsigned int)u) << 16);
}
__device__ __forceinline__ unsigned short f2bf(float f) {
    unsigned int u = __float_as_uint(f);
    unsigned int r = u + 0x7FFFu + ((u >> 16) & 1u);
    return (unsigned short)(r >> 16);
}
__device__ __forceinline__ unsigned int pack2(float a, float b) {
    return (unsigned int)f2bf(a) | ((unsigned int)f2bf(b) << 16);
}
__device__ __forceinline__ void unpack8(uint4 v, float* f) {
    f[0] = bf2f((unsigned short)(v.x & 0xffff)); f[1] = bf2f((unsigned short)(v.x >> 16));
    f[2] = bf2f((unsigned short)(v.y & 0xffff)); f[3] = bf2f((unsigned short)(v.y >> 16));
    f[4] = bf2f((unsigned short)(v.z & 0xffff)); f[5] = bf2f((unsigned short)(v.z >> 16));
    f[6] = bf2f((unsigned short)(v.w & 0xffff)); f[7] = bf2f((unsigned short)(v.w >> 16));
}

// ---------------------------------------------------------------------------
// Index dtype detection + canonicalization
// ---------------------------------------------------------------------------
__global__ void detect_kernel(const int* __restrict__ ei, int* __restrict__ flag)
{
    int lane = threadIdx.x;
    int v = ei[2 * lane + 1];
    unsigned long long b = __ballot(v != 0);
    if (lane == 0) *flag = (b != 0ULL) ? 1 : 0;
}

__global__ void normidx_kernel(const int* __restrict__ ei, const int* __restrict__ flag,
                               int* __restrict__ s32, int* __restrict__ d32)
{
    int e = blockIdx.x * blockDim.x + threadIdx.x;
    if (e >= NEDGES) return;
    int s, d;
    if (*flag) { s = ei[e]; d = ei[NEDGES + e]; }
    else       { s = ei[2 * e]; d = ei[2 * (NEDGES + e)]; }
    s32[e] = min(max(s, 0), NNODES - 1);
    d32[e] = min(max(d, 0), NNODES - 1);
}

__global__ void degree_kernel(const int* __restrict__ dst, int* __restrict__ deg)
{
    int e = blockIdx.x * blockDim.x + threadIdx.x;
    if (e < NEDGES) atomicAdd(&deg[dst[e]], 1);
}

// ---------------------------------------------------------------------------
// Exclusive scan over deg[0..NNODES) -> off, cursor. One 1024-thread block.
// ---------------------------------------------------------------------------
#define SCAN_T 1024
__global__ void scan_kernel(const int* __restrict__ deg, int* __restrict__ off,
                            int* __restrict__ cursor)
{
    __shared__ int part[SCAN_T];
    const int t = threadIdx.x;
    const int CH = (NNODES + SCAN_T - 1) / SCAN_T;
    const int base = t * CH;
    int s = 0;
    for (int i = 0; i < CH; ++i) {
        int idx = base + i;
        if (idx < NNODES) s += deg[idx];
    }
    part[t] = s;
    __syncthreads();
    for (int d = 1; d < SCAN_T; d <<= 1) {
        int v = (t >= d) ? part[t - d] : 0;
        __syncthreads();
        part[t] += v;
        __syncthreads();
    }
    int run = (t == 0) ? 0 : part[t - 1];
    for (int i = 0; i < CH; ++i) {
        int idx = base + i;
        if (idx < NNODES) {
            off[idx] = run;
            cursor[idx] = run;
            run += deg[idx];
        }
    }
    if (t == SCAN_T - 1) off[NNODES] = run;
}

__global__ void scatter_kernel(const int* __restrict__ s32, const int* __restrict__ d32,
                               int* __restrict__ cursor,
                               int* __restrict__ sp, int* __restrict__ dp, int* __restrict__ ep)
{
    int e = blockIdx.x * blockDim.x + threadIdx.x;
    if (e >= NEDGES) return;
    int d = d32[e];
    int p = atomicAdd(&cursor[d], 1);
    sp[p] = s32[e];
    dp[p] = d;
    ep[p] = e;
}

// ---------------------------------------------------------------------------
// Weight swizzle: W [L][Ktot][128] fp32 -> fragment-ordered bf16.
// out[l][(c*8+nt)*512 + lane*8 + j] = W[l][k0 + c*32 + (lane>>4)*8 + j][nt*16 + (lane&15)]
// A wave's B-fragment load becomes one coalesced 1024B read.
// ---------------------------------------------------------------------------
__global__ void swizzle_kernel(const float* __restrict__ W, unsigned short* __restrict__ out,
                               int k0, int Ktot, int Ksw, int L)
{
    long per = (long)Ksw * 128;
    long idx = (long)blockIdx.x * 256 + threadIdx.x;
    if (idx >= (long)L * per) return;
    int l = (int)(idx / per);
    int o = (int)(idx % per);
    int j    = o & 7;
    int lane = (o >> 3) & 63;
    int frag = o >> 9;                 // c*8 + nt
    int c = frag >> 3, nt = frag & 7;
    int k = k0 + c * 32 + (lane >> 4) * 8 + j;
    int n = nt * 16 + (lane & 15);
    out[idx] = f2bf(W[(long)l * Ktot * 128 + (long)k * 128 + n]);
}

// ---------------------------------------------------------------------------
// Encoder into permuted + SWIZZLED ef layout.
// ef_s tile t (128 edges): addr = t*16384 + ((r>>4)*4 + c)*512 + (q*16 + (r&15))*8 + j
//   where r = p&127, k = c*32 + q*8 + j.
// Thread handles (p, s): s -> c=s>>2, q=s&3; computes 8 outputs.
// ---------------------------------------------------------------------------
__global__ void encode_kernel(const float* __restrict__ ea,
                              const float* __restrict__ w,
                              const float* __restrict__ b,
                              const int* __restrict__ ep,
                              unsigned short* __restrict__ efs)
{
    int idx = blockIdx.x * blockDim.x + threadIdx.x;
    int p = idx >> 4;
    if (p >= NEDGES) return;
    int s = idx & 15;
    int cc = s >> 2, qq = s & 3;
    int kb = cc * 32 + qq * 8;
    int e = ep[p];
    float a0 = ea[e * 3 + 0], a1 = ea[e * 3 + 1], a2 = ea[e * 3 + 2];
    unsigned short o[8];
#pragma unroll
    for (int j = 0; j < 8; ++j) {
        int k = kb + j;
        float v = fmaf(a0, w[0 * HIDDEN + k],
                  fmaf(a1, w[1 * HIDDEN + k],
                  fmaf(a2, w[2 * HIDDEN + k], b[k])));
        o[j] = f2bf(v);
    }
    int r = p & 127;
    long addr = (long)(p >> 7) * 16384 + (long)(((r >> 4) * 4 + cc) * 512) + ((qq * 16 + (r & 15)) * 8);
    *(uint4*)(efs + addr) = *(uint4*)o;
}

// ---------------------------------------------------------------------------
// MFMA edge layer, swizzled operands, 128-edge tile, 2 barriers:
//   GEMM1: A = ef_s fragments (coalesced global), B = W1C swizzled (L2-hot)
//   H = relu(pre + Xa[dst] + Xb[src] + b1) -> Hs
//   GEMM2: A = Hs (wave-private), B = W2S swizzled
//   ef_s += m ; segmented-reduce m into sums[dst]
// ---------------------------------------------------------------------------
__global__ __launch_bounds__(256, 4)
void edge_layer_mfma(const unsigned short* __restrict__ Xa,   // [N][128] bf16 row-major
                     const unsigned short* __restrict__ Xb,
                     unsigned short* __restrict__ efs,        // swizzled
                     float* __restrict__ sums,
                     const int* __restrict__ sp,
                     const int* __restrict__ dp,
                     const unsigned short* __restrict__ W1C,  // swizzled [4][8][512]
                     const float* __restrict__ b1,
                     const unsigned short* __restrict__ W2S,  // swizzled [4][8][512]
                     const float* __restrict__ b2)
{
    __shared__ __align__(16) unsigned short Hs[128 * 136];   // 34816 B
    __shared__ int dv[128];
    __shared__ int sv[128];

    const int tid = threadIdx.x;
    const long eb = (long)blockIdx.x * 128;
    if (tid < 128) dv[tid]       = dp[eb + tid];
    else           sv[tid - 128] = sp[eb + tid - 128];

    const int lane = tid & 63;
    const int wv   = tid >> 6;
    const int mn   = lane & 15;
    const int q    = lane >> 4;

    unsigned short* tile = efs + (long)blockIdx.x * 16384;

    f32x4 acc[2][8];
#pragma unroll
    for (int h = 0; h < 2; ++h)
#pragma unroll
        for (int t = 0; t < 8; ++t) acc[h][t] = (f32x4)0.0f;

    // ---- GEMM1: ef @ W1c — all operands direct, coalesced, no LDS ----
#pragma unroll
    for (int c = 0; c < 4; ++c) {
        short8 af0 = *(const short8*)(tile + ((wv * 8 + 0 + c) * 512) + lane * 8);
        short8 af1 = *(const short8*)(tile + ((wv * 8 + 4 + c) * 512) + lane * 8);
#pragma unroll
        for (int nt = 0; nt < 8; ++nt) {
            short8 bf = *(const short8*)(W1C + (c * 8 + nt) * 512 + lane * 8);
            acc[0][nt] = __builtin_amdgcn_mfma_f32_16x16x32_bf16(af0, bf, acc[0][nt], 0, 0, 0);
            acc[1][nt] = __builtin_amdgcn_mfma_f32_16x16x32_bf16(af1, bf, acc[1][nt], 0, 0, 0);
        }
    }
    __syncthreads();   // dv/sv visible

    // ---- H = relu(acc + Xa[dst] + Xb[src] + b1) -> Hs bf16 (wave-private rows)
#pragma unroll
    for (int h = 0; h < 2; ++h)
#pragma unroll
        for (int r = 0; r < 4; ++r) {
            const int row = wv * 32 + h * 16 + q * 4 + r;
            const long ba = (long)dv[row] * HIDDEN;
            const long bb = (long)sv[row] * HIDDEN;
#pragma unroll
            for (int nt = 0; nt < 8; ++nt) {
                const int col = nt * 16 + mn;
                float add = bf2f(Xa[ba + col]) + bf2f(Xb[bb + col]) + b1[col];
                float hv = fmaxf(acc[h][nt][r] + add, 0.0f);
                Hs[row * 136 + col] = f2bf(hv);
            }
        }

    // ---- GEMM2: H @ W2 — A from Hs (wave-private, no barrier), B direct ----
    f32x4 acc2[2][8];
#pragma unroll
    for (int h = 0; h < 2; ++h)
#pragma unroll
        for (int t = 0; t < 8; ++t) acc2[h][t] = (f32x4)0.0f;
#pragma unroll
    for (int c = 0; c < 4; ++c) {
        short8 af0 = *(short8*)&Hs[(wv * 32 + mn) * 136 + (c << 5) + (q << 3)];
        short8 af1 = *(short8*)&Hs[(wv * 32 + 16 + mn) * 136 + (c << 5) + (q << 3)];
#pragma unroll
        for (int nt = 0; nt < 8; ++nt) {
            short8 bf = *(const short8*)(W2S + (c * 8 + nt) * 512 + lane * 8);
            acc2[0][nt] = __builtin_amdgcn_mfma_f32_16x16x32_bf16(af0, bf, acc2[0][nt], 0, 0, 0);
            acc2[1][nt] = __builtin_amdgcn_mfma_f32_16x16x32_bf16(af1, bf, acc2[1][nt], 0, 0, 0);
        }
    }

    // ---- m = acc2 + b2 -> Hs (wave-private rows, in-order same-wave DS) ----
#pragma unroll
    for (int h = 0; h < 2; ++h)
#pragma unroll
        for (int nt = 0; nt < 8; ++nt) {
            float b2v = b2[nt * 16 + mn];
#pragma unroll
            for (int r = 0; r < 4; ++r) {
                Hs[(wv * 32 + h * 16 + q * 4 + r) * 136 + nt * 16 + mn] = f2bf(acc2[h][nt][r] + b2v);
            }
        }
    __syncthreads();

    // ---- ef_s += m : swizzled chunks, fully coalesced ----
#pragma unroll
    for (int i = 0; i < 8; ++i) {
        const int ch = tid + i * 256;          // 0..2047
        const int s  = ch >> 6;                // segment 0..31
        const int l8 = ch & 63;                // lane-in-frag
        const int row = (s >> 2) * 16 + (l8 & 15);
        const int k   = (s & 3) * 32 + ((l8 >> 4) << 3);
        uint4 mh = *(uint4*)&Hs[row * 136 + k];
        unsigned short* ep_ = tile + s * 512 + l8 * 8;
        uint4 eo = *(const uint4*)ep_;
        float m[8], e[8];
        unpack8(mh, m);
        unpack8(eo, e);
        uint4 nw;
        nw.x = pack2(e[0] + m[0], e[1] + m[1]);
        nw.y = pack2(e[2] + m[2], e[3] + m[3]);
        nw.z = pack2(e[4] + m[4], e[5] + m[5]);
        nw.w = pack2(e[6] + m[6], e[7] + m[7]);
        *(uint4*)ep_ = nw;
    }

    // ---- segmented reduction by dst-run: one atomic row per run ----
    {
        const int cp = (tid & 63) << 1;
        const int qr = tid >> 6;
        float s0 = 0.0f, s1 = 0.0f;
        int cur = dv[qr * 32];
        for (int r = 0; r < 32; ++r) {
            const int row = qr * 32 + r;
            const int d = dv[row];
            if (d != cur) {
                atomicAdd(&sums[(long)cur * HIDDEN + cp], s0);
                atomicAdd(&sums[(long)cur * HIDDEN + cp + 1], s1);
                s0 = 0.0f; s1 = 0.0f;
                cur = d;
            }
            unsigned int u = *(unsigned int*)&Hs[row * 136 + cp];
            s0 += bf2f((unsigned short)(u & 0xffff));
            s1 += bf2f((unsigned short)(u >> 16));
        }
        atomicAdd(&sums[(long)cur * HIDDEN + cp], s0);
        atomicAdd(&sums[(long)cur * HIDDEN + cp + 1], s1);
    }
}

// ---------------------------------------------------------------------------
// MFMA node layer, swizzled-B, full-A staged once. 64 nodes/block, 2 barriers.
//   GEMM1: A = [x | sums*cInv] staged bf16 (stride 264), B = N1S direct
//   GEMM2/Xa/Xb: A from Hs (aliased over As), B direct
// ---------------------------------------------------------------------------
__global__ __launch_bounds__(256, 4)
void node_layer_mfma(float* __restrict__ x,
                     float* __restrict__ sums,
                     const int* __restrict__ deg,
                     const unsigned short* __restrict__ N1S,  // swizzled [8][8][512]
                     const float* __restrict__ b1,
                     const unsigned short* __restrict__ N2S,  // swizzled [4][8][512]
                     const float* __restrict__ b2,
                     const unsigned short* __restrict__ W1An, // next layer [4][8][512] (or null)
                     const unsigned short* __restrict__ W1Bn,
                     unsigned short* __restrict__ Xa,
                     unsigned short* __restrict__ Xb)
{
    __shared__ __align__(16) unsigned short As[64 * 264];    // 33792 B; Hs aliased at base
    unsigned short* Hs = As;                                 // 64 x 136 after GEMM1

    const int tid = threadIdx.x;
    const long n0 = (long)blockIdx.x * 64;
    const int lane = tid & 63;
    const int wv   = tid >> 6;
    const int mn   = lane & 15;
    const int q    = lane >> 4;

    // ---- stage A = [x | sums*cInv] bf16 (coalesced reads) ----
    {
        const int row = tid >> 2;
        const int qt  = (tid & 3) << 5;
        long nr = n0 + row; if (nr >= NNODES) nr = NNODES - 1;
        const float ci = 1.0f / fmaxf((float)deg[nr], 1.0f);
        const float* xr = x + nr * HIDDEN + qt;
        const float* sr = sums + nr * HIDDEN + qt;
#pragma unroll
        for (int i = 0; i < 4; ++i) {
            float4 v0 = *(const float4*)(xr + i * 8);
            float4 v1 = *(const float4*)(xr + i * 8 + 4);
            uint4 u;
            u.x = pack2(v0.x, v0.y); u.y = pack2(v0.z, v0.w);
            u.z = pack2(v1.x, v1.y); u.w = pack2(v1.z, v1.w);
            *(uint4*)&As[row * 264 + qt + i * 8] = u;
            float4 w0 = *(const float4*)(sr + i * 8);
            float4 w1 = *(const float4*)(sr + i * 8 + 4);
            u.x = pack2(w0.x * ci, w0.y * ci); u.y = pack2(w0.z * ci, w0.w * ci);
            u.z = pack2(w1.x * ci, w1.y * ci); u.w = pack2(w1.z * ci, w1.w * ci);
            *(uint4*)&As[row * 264 + 128 + qt + i * 8] = u;
        }
    }
    __syncthreads();

    // ---- GEMM1: K=256, 8 k-steps, A from As, B direct ----
    f32x4 acc[8];
#pragma unroll
    for (int t = 0; t < 8; ++t) acc[t] = (f32x4)0.0f;
#pragma unroll
    for (int c = 0; c < 8; ++c) {
        short8 af = *(short8*)&As[(wv * 16 + mn) * 264 + (c << 5) + (q << 3)];
#pragma unroll
        for (int nt = 0; nt < 8; ++nt) {
            short8 bf = *(const short8*)(N1S + (c * 8 + nt) * 512 + lane * 8);
            acc[nt] = __builtin_amdgcn_mfma_f32_16x16x32_bf16(af, bf, acc[nt], 0, 0, 0);
        }
    }
    __syncthreads();   // all As reads done before Hs alias write

    // ---- H = relu(acc + b1) -> Hs (wave-private rows) ----
#pragma unroll
    for (int nt = 0; nt < 8; ++nt) {
        float b1v = b1[nt * 16 + mn];
#pragma unroll
        for (int r = 0; r < 4; ++r) {
            float hv = fmaxf(acc[nt][r] + b1v, 0.0f);
            Hs[(wv * 16 + q * 4 + r) * 136 + nt * 16 + mn] = f2bf(hv);
        }
    }

    // ---- GEMM2: H @ N2 (A wave-private from Hs, B direct) ----
    f32x4 acc2[8];
#pragma unroll
    for (int t = 0; t < 8; ++t) acc2[t] = (f32x4)0.0f;
#pragma unroll
    for (int c = 0; c < 4; ++c) {
        short8 af = *(short8*)&Hs[(wv * 16 + mn) * 136 + (c << 5) + (q << 3)];
#pragma unroll
        for (int nt = 0; nt < 8; ++nt) {
            short8 bf = *(const short8*)(N2S + (c * 8 + nt) * 512 + lane * 8);
            acc2[nt] = __builtin_amdgcn_mfma_f32_16x16x32_bf16(af, bf, acc2[nt], 0, 0, 0);
        }
    }

    // ---- xnew = x + acc2 + b2 (fp32); stage xnew bf16 into Hs (in place) ----
#pragma unroll
    for (int nt = 0; nt < 8; ++nt) {
        float b2v = b2[nt * 16 + mn];
#pragma unroll
        for (int r = 0; r < 4; ++r) {
            long row = n0 + wv * 16 + q * 4 + r;
            float xn = 0.0f;
            if (row < NNODES) {
                float* p = x + row * HIDDEN + nt * 16 + mn;
                xn = *p + acc2[nt][r] + b2v;
                *p = xn;
            }
            Hs[(wv * 16 + q * 4 + r) * 136 + nt * 16 + mn] = f2bf(xn);
        }
    }

    // ---- Xa/Xb for next layer: xnew @ W1a / W1b (A wave-private) ----
    if (W1An) {
#pragma unroll
        for (int half = 0; half < 2; ++half) {
            const unsigned short* Bsw = half ? W1Bn : W1An;
            f32x4 accN[8];
#pragma unroll
            for (int t = 0; t < 8; ++t) accN[t] = (f32x4)0.0f;
#pragma unroll
            for (int c = 0; c < 4; ++c) {
                short8 af = *(short8*)&Hs[(wv * 16 + mn) * 136 + (c << 5) + (q << 3)];
#pragma unroll
                for (int nt = 0; nt < 8; ++nt) {
                    short8 bf = *(const short8*)(Bsw + (c * 8 + nt) * 512 + lane * 8);
                    accN[nt] = __builtin_amdgcn_mfma_f32_16x16x32_bf16(af, bf, accN[nt], 0, 0, 0);
                }
            }
            unsigned short* Xout = half ? Xb : Xa;
#pragma unroll
            for (int nt = 0; nt < 8; ++nt) {
#pragma unroll
                for (int r = 0; r < 4; ++r) {
                    long row = n0 + wv * 16 + q * 4 + r;
                    if (row < NNODES) {
                        Xout[row * HIDDEN + nt * 16 + mn] = f2bf(accN[nt][r]);
                    }
                }
            }
        }
    }

    // ---- zero own sums rows for the next layer ----
    {
        const int row = tid >> 2;
        const int qt  = (tid & 3) << 5;
        long nr = n0 + row;
        if (nr < NNODES) {
            float4 z = make_float4(0.f, 0.f, 0.f, 0.f);
            float* p = sums + nr * HIDDEN + qt;
#pragma unroll
            for (int i = 0; i < 8; ++i) ((float4*)p)[i] = z;
        }
    }
}

// ---------------------------------------------------------------------------
// Decoder + row L2-normalize (one wave per node)
// ---------------------------------------------------------------------------
__global__ void decode_kernel(const float* __restrict__ x,
                              const float* __restrict__ w,
                              const float* __restrict__ b,
                              float* __restrict__ out)
{
    int gid = blockIdx.x * blockDim.x + threadIdx.x;
    int node = gid >> 6;
    int lane = threadIdx.x & 63;
    if (node >= NNODES) return;
    float a0 = 0.f, a1 = 0.f, a2 = 0.f;
#pragma unroll
    for (int k = lane; k < HIDDEN; k += 64) {
        float xv = x[(long)node * HIDDEN + k];
        a0 = fmaf(xv, w[k * 3 + 0], a0);
        a1 = fmaf(xv, w[k * 3 + 1], a1);
        a2 = fmaf(xv, w[k * 3 + 2], a2);
    }
#pragma unroll
    for (int off = 32; off > 0; off >>= 1) {
        a0 += __shfl_down(a0, off);
        a1 += __shfl_down(a1, off);
        a2 += __shfl_down(a2, off);
    }
    if (lane == 0) {
        a0 += b[0]; a1 += b[1]; a2 += b[2];
        float nrm = sqrtf(a0 * a0 + a1 * a1 + a2 * a2);
        float inv = 1.0f / fmaxf(nrm, 1e-12f);
        out[(long)node * 3 + 0] = a0 * inv;
        out[(long)node * 3 + 1] = a1 * inv;
        out[(long)node * 3 + 2] = a2 * inv;
    }
}

// ---------------------------------------------------------------------------
extern "C" void kernel_launch(void* const* d_in, const int* in_sizes, int n_in,
                              void* d_out, int out_size, void* d_ws, size_t ws_size,
                              hipStream_t stream)
{
    const float* edge_attr = (const float*)d_in[1];
    const int*   ei        = (const int*)d_in[2];
    const float* enc_w     = (const float*)d_in[3];
    const float* enc_b     = (const float*)d_in[4];
    const float* dec_w     = (const float*)d_in[5];
    const float* dec_b     = (const float*)d_in[6];
    const float* edge_w1   = (const float*)d_in[7];
    const float* edge_b1   = (const float*)d_in[8];
    const float* edge_w2   = (const float*)d_in[9];
    const float* edge_b2   = (const float*)d_in[10];
    const float* node_w1   = (const float*)d_in[11];
    const float* node_b1   = (const float*)d_in[12];
    const float* node_w2   = (const float*)d_in[13];
    const float* node_b2   = (const float*)d_in[14];

    // workspace layout (bytes), 16B-aligned, total ~255.4 MB
    char* ws = (char*)d_ws;
    unsigned short* efs = (unsigned short*)(ws);                  // 163,840,000 (swizzled)
    float* x      = (float*)(ws + 163840000L);                    //  25,600,000
    float* sums   = (float*)(ws + 189440000L);                    //  25,600,000
    int*   src32  = (int*)  (ws + 215040000L);                    //   2,560,000
    int*   dst32  = (int*)  (ws + 217600000L);                    //   2,560,000
    int*   sp     = (int*)  (ws + 220160000L);                    //   2,560,000
    int*   dp     = (int*)  (ws + 222720000L);                    //   2,560,000
    int*   eperm  = (int*)  (ws + 225280000L);                    //   2,560,000
    int*   deg    = (int*)  (ws + 227840000L);                    //     200,704
    int*   off    = (int*)  (ws + 228040704L);                    //     200,704
    int*   cursor = (int*)  (ws + 228241408L);                    //     200,704
    int*   flag   = (int*)  (ws + 228442112L);                    //          64
    unsigned short* W1A = (unsigned short*)(ws + 228442176L);     //     196,608
    unsigned short* W1B = (unsigned short*)(ws + 228638784L);     //     196,608
    unsigned short* W1C = (unsigned short*)(ws + 228835392L);     //     196,608
    unsigned short* W2S = (unsigned short*)(ws + 229032000L);     //     196,608
    unsigned short* N1S = (unsigned short*)(ws + 229228608L);     //     393,216
    unsigned short* N2S = (unsigned short*)(ws + 229621824L);     //     196,608
    unsigned short* Xa  = (unsigned short*)(ws + 229818432L);     //  12,800,000
    unsigned short* Xb  = (unsigned short*)(ws + 242618432L);     //  12,800,000
    // end: 255,418,432

    float* out = (float*)d_out;

    hipMemsetAsync(x, 0, (size_t)NNODES * HIDDEN * sizeof(float), stream);
    hipMemsetAsync(sums, 0, (size_t)NNODES * HIDDEN * sizeof(float), stream);
    hipMemsetAsync(deg, 0, 200704, stream);
    hipMemsetAsync(Xa, 0, 25600000, stream);   // Xa + Xb (contiguous)

    detect_kernel<<<1, 64, 0, stream>>>(ei, flag);
    normidx_kernel<<<(NEDGES + 255) / 256, 256, 0, stream>>>(ei, flag, src32, dst32);
    degree_kernel<<<(NEDGES + 255) / 256, 256, 0, stream>>>(dst32, deg);
    scan_kernel<<<1, SCAN_T, 0, stream>>>(deg, off, cursor);
    scatter_kernel<<<(NEDGES + 255) / 256, 256, 0, stream>>>(src32, dst32, cursor, sp, dp, eperm);
    encode_kernel<<<(NEDGES * 16 + 255) / 256, 256, 0, stream>>>(edge_attr, enc_w, enc_b, eperm, efs);

    swizzle_kernel<<<(6 * 128 * 128 + 255) / 256, 256, 0, stream>>>(edge_w1, W1A, 0,   384, 128, 6);
    swizzle_kernel<<<(6 * 128 * 128 + 255) / 256, 256, 0, stream>>>(edge_w1, W1B, 128, 384, 128, 6);
    swizzle_kernel<<<(6 * 128 * 128 + 255) / 256, 256, 0, stream>>>(edge_w1, W1C, 256, 384, 128, 6);
    swizzle_kernel<<<(6 * 128 * 128 + 255) / 256, 256, 0, stream>>>(edge_w2, W2S, 0,   128, 128, 6);
    swizzle_kernel<<<(6 * 256 * 128 + 255) / 256, 256, 0, stream>>>(node_w1, N1S, 0,   256, 256, 6);
    swizzle_kernel<<<(6 * 128 * 128 + 255) / 256, 256, 0, stream>>>(node_w2, N2S, 0,   128, 128, 6);

    for (int l = 0; l < NLAYERS; ++l) {
        edge_layer_mfma<<<NEDGES / 128, 256, 0, stream>>>(
            Xa, Xb, efs, sums, sp, dp,
            W1C + (long)l * 16384, edge_b1 + (long)l * HIDDEN,
            W2S + (long)l * 16384, edge_b2 + (long)l * HIDDEN);
        const unsigned short* w1an = (l + 1 < NLAYERS) ? (W1A + (long)(l + 1) * 16384) : nullptr;
        const unsigned short* w1bn = (l + 1 < NLAYERS) ? (W1B + (long)(l + 1) * 16384) : nullptr;
        node_layer_mfma<<<(NNODES + 63) / 64, 256, 0, stream>>>(
            x, sums, deg,
            N1S + (long)l * 32768, node_b1 + (long)l * HIDDEN,
            N2S + (long)l * 16384, node_b2 + (long)l * HIDDEN,
            w1an, w1bn, Xa, Xb);
    }

    decode_kernel<<<(NNODES * 64 + 255) / 256, 256, 0, stream>>>(x, dec_w, dec_b, out);
}

// Round 10
// 1544.493 us; speedup vs baseline: 1.3624x; 1.3624x over previous
//
#include <hip/hip_runtime.h>
#include <cstdint>

#define HIDDEN  128
#define NLAYERS 6
#define NNODES  50000
#define NEDGES  640000

typedef short short8 __attribute__((ext_vector_type(8)));
typedef float f32x4  __attribute__((ext_vector_type(4)));

// ---- bf16 <-> f32 helpers (RNE) -------------------------------------------
__device__ __forceinline__ float bf2f(unsigned short u) {
    return __uint_as_float(((unsigned int)u) << 16);
}
__device__ __forceinline__ unsigned short f2bf(float f) {
    unsigned int u = __float_as_uint(f);
    unsigned int r = u + 0x7FFFu + ((u >> 16) & 1u);
    return (unsigned short)(r >> 16);
}
__device__ __forceinline__ unsigned int pack2(float a, float b) {
    return (unsigned int)f2bf(a) | ((unsigned int)f2bf(b) << 16);
}
__device__ __forceinline__ void unpack8(uint4 v, float* f) {
    f[0] = bf2f((unsigned short)(v.x & 0xffff)); f[1] = bf2f((unsigned short)(v.x >> 16));
    f[2] = bf2f((unsigned short)(v.y & 0xffff)); f[3] = bf2f((unsigned short)(v.y >> 16));
    f[4] = bf2f((unsigned short)(v.z & 0xffff)); f[5] = bf2f((unsigned short)(v.z >> 16));
    f[6] = bf2f((unsigned short)(v.w & 0xffff)); f[7] = bf2f((unsigned short)(v.w >> 16));
}

// ---------------------------------------------------------------------------
// Index dtype detection + canonicalization
// ---------------------------------------------------------------------------
__global__ void detect_kernel(const int* __restrict__ ei, int* __restrict__ flag)
{
    int lane = threadIdx.x;
    int v = ei[2 * lane + 1];
    unsigned long long b = __ballot(v != 0);
    if (lane == 0) *flag = (b != 0ULL) ? 1 : 0;
}

__global__ void normidx_kernel(const int* __restrict__ ei, const int* __restrict__ flag,
                               int* __restrict__ s32, int* __restrict__ d32)
{
    int e = blockIdx.x * blockDim.x + threadIdx.x;
    if (e >= NEDGES) return;
    int s, d;
    if (*flag) { s = ei[e]; d = ei[NEDGES + e]; }
    else       { s = ei[2 * e]; d = ei[2 * (NEDGES + e)]; }
    s32[e] = min(max(s, 0), NNODES - 1);
    d32[e] = min(max(d, 0), NNODES - 1);
}

__global__ void degree_kernel(const int* __restrict__ dst, int* __restrict__ deg)
{
    int e = blockIdx.x * blockDim.x + threadIdx.x;
    if (e < NEDGES) atomicAdd(&deg[dst[e]], 1);
}

// ---------------------------------------------------------------------------
// Exclusive scan over deg[0..NNODES) -> off, cursor. One 1024-thread block.
// ---------------------------------------------------------------------------
#define SCAN_T 1024
__global__ void scan_kernel(const int* __restrict__ deg, int* __restrict__ off,
                            int* __restrict__ cursor)
{
    __shared__ int part[SCAN_T];
    const int t = threadIdx.x;
    const int CH = (NNODES + SCAN_T - 1) / SCAN_T;
    const int base = t * CH;
    int s = 0;
    for (int i = 0; i < CH; ++i) {
        int idx = base + i;
        if (idx < NNODES) s += deg[idx];
    }
    part[t] = s;
    __syncthreads();
    for (int d = 1; d < SCAN_T; d <<= 1) {
        int v = (t >= d) ? part[t - d] : 0;
        __syncthreads();
        part[t] += v;
        __syncthreads();
    }
    int run = (t == 0) ? 0 : part[t - 1];
    for (int i = 0; i < CH; ++i) {
        int idx = base + i;
        if (idx < NNODES) {
            off[idx] = run;
            cursor[idx] = run;
            run += deg[idx];
        }
    }
    if (t == SCAN_T - 1) off[NNODES] = run;
}

__global__ void scatter_kernel(const int* __restrict__ s32, const int* __restrict__ d32,
                               int* __restrict__ cursor,
                               int* __restrict__ sp, int* __restrict__ dp, int* __restrict__ ep)
{
    int e = blockIdx.x * blockDim.x + threadIdx.x;
    if (e >= NEDGES) return;
    int d = d32[e];
    int p = atomicAdd(&cursor[d], 1);
    sp[p] = s32[e];
    dp[p] = d;
    ep[p] = e;
}

// ---------------------------------------------------------------------------
// Weight transpose+convert: W [L][K][N] fp32 -> WT [L][N][K] bf16
// ---------------------------------------------------------------------------
__global__ void transpose_kernel(const float* __restrict__ W, unsigned short* __restrict__ WT,
                                 int K, int N, int L)
{
    long idx = (long)blockIdx.x * 256 + threadIdx.x;
    long tot = (long)L * K * N;
    if (idx >= tot) return;
    int kn = (int)(idx % ((long)K * N));
    int l  = (int)(idx / ((long)K * N));
    int k = kn / N;
    int n = kn % N;
    WT[(long)l * K * N + (long)n * K + k] = f2bf(W[idx]);
}

// ---------------------------------------------------------------------------
// Encoder into permuted layout: ef[p] = enc(ea[ep[p]])
// ---------------------------------------------------------------------------
__global__ void encode_kernel(const float* __restrict__ ea,
                              const float* __restrict__ w,
                              const float* __restrict__ b,
                              const int* __restrict__ ep,
                              unsigned short* __restrict__ ef)
{
    int idx = blockIdx.x * blockDim.x + threadIdx.x;
    int p = idx >> 5;
    if (p >= NEDGES) return;
    int e = ep[p];
    int j = (idx & 31) << 2;
    float a0 = ea[e * 3 + 0], a1 = ea[e * 3 + 1], a2 = ea[e * 3 + 2];
    float4 w0 = *(const float4*)(w + 0 * HIDDEN + j);
    float4 w1 = *(const float4*)(w + 1 * HIDDEN + j);
    float4 w2 = *(const float4*)(w + 2 * HIDDEN + j);
    float4 bb = *(const float4*)(b + j);
    ushort4 o;
    o.x = f2bf(fmaf(a0, w0.x, fmaf(a1, w1.x, fmaf(a2, w2.x, bb.x))));
    o.y = f2bf(fmaf(a0, w0.y, fmaf(a1, w1.y, fmaf(a2, w2.y, bb.y))));
    o.z = f2bf(fmaf(a0, w0.z, fmaf(a1, w1.z, fmaf(a2, w2.z, bb.z))));
    o.w = f2bf(fmaf(a0, w0.w, fmaf(a1, w1.w, fmaf(a2, w2.w, bb.w))));
    *(ushort4*)(ef + (long)p * HIDDEN + j) = o;
}

// ---------------------------------------------------------------------------
// MFMA edge layer (r6 structure + vectorized gather + register ef_old):
//   GEMM1: pre = ef @ W1c (LDS-staged, prefetched); ef_old frags kept in regs
//   pre -> Hs (C-layout, own band); H = relu(pre + Xa[dst]+Xb[src]+b1)
//     computed by row-major half-row threads (vector gather) in place in Hs
//   GEMM2: m = H @ W2 (A from Hs wave-private, Bs staged)
//   m -> Hs; ef_new = ef_old(regs) + m written in A-frag order (64B sectors);
//   segmented reduction into sums (all epilogue own-band, barrier-free)
// 128 edges x 128 out per block, 4 waves x 32 rows.
// ---------------------------------------------------------------------------
__global__ __launch_bounds__(256, 3)
void edge_layer_mfma(const unsigned short* __restrict__ Xa,   // [N][128] bf16
                     const unsigned short* __restrict__ Xb,   // [N][128] bf16
                     unsigned short* __restrict__ ef,
                     float* __restrict__ sums,
                     const int* __restrict__ sp,
                     const int* __restrict__ dp,
                     const unsigned short* __restrict__ W1T,  // [128][384] bf16; W1c at k+256
                     const float* __restrict__ b1,
                     const unsigned short* __restrict__ W2T,  // [128][128] bf16
                     const float* __restrict__ b2)
{
    // 0      .. 34816 : Hs (128 x 136) / As (128 x 40, 10240 B) aliased
    // 34816  .. 45056 : Bs (128 x 40)
    __shared__ __align__(16) unsigned char buf[45056];
    unsigned short* As = (unsigned short*)buf;
    unsigned short* Hs = (unsigned short*)buf;
    unsigned short* Bs = (unsigned short*)(buf + 34816);
    __shared__ int dv[128];
    __shared__ int sv[128];

    const int tid = threadIdx.x;
    const long eb = (long)blockIdx.x * 128;
    if (tid < 128) dv[tid]       = dp[eb + tid];
    else           sv[tid - 128] = sp[eb + tid - 128];

    const int lane = tid & 63;
    const int wv   = tid >> 6;
    const int mn   = lane & 15;
    const int q    = lane >> 4;
    const int rr   = tid >> 1;          // staging row 0..127
    const int o    = (tid & 1) << 4;    // 16-short half
    const int bn   = tid >> 1;
    const int bk   = (tid & 1) << 4;

    f32x4 acc[2][8];
#pragma unroll
    for (int h = 0; h < 2; ++h)
#pragma unroll
        for (int t = 0; t < 8; ++t) acc[h][t] = (f32x4)0.0f;

    short8 efold0[4], efold1[4];        // ef_old A-fragments (32 VGPRs)

    uint4 pa0, pa1, pw0, pw1;
    {   // chunk 0 loads
        const unsigned short* epp = ef + (eb + rr) * HIDDEN + o;
        pa0 = *(const uint4*)epp;
        pa1 = *(const uint4*)(epp + 8);
        const unsigned short* wp = W1T + (long)bn * 384 + 256 + bk;
        pw0 = *(const uint4*)wp;
        pw1 = *(const uint4*)(wp + 8);
    }

    // ---- GEMM1: ef @ W1c, 4 k-steps of 32, register-prefetched ----
    for (int c = 0; c < 4; ++c) {
        *(uint4*)&As[rr * 40 + o]      = pa0;
        *(uint4*)&As[rr * 40 + o + 8]  = pa1;
        *(uint4*)&Bs[bn * 40 + bk]     = pw0;
        *(uint4*)&Bs[bn * 40 + bk + 8] = pw1;
        __syncthreads();

        if (c + 1 < 4) {
            const int cn = c + 1;
            const unsigned short* epp = ef + (eb + rr) * HIDDEN + (cn << 5) + o;
            pa0 = *(const uint4*)epp;
            pa1 = *(const uint4*)(epp + 8);
            const unsigned short* wp = W1T + (long)bn * 384 + 256 + (cn << 5) + bk;
            pw0 = *(const uint4*)wp;
            pw1 = *(const uint4*)(wp + 8);
        }

        short8 af0 = *(short8*)&As[(wv * 32 + mn) * 40 + (q << 3)];
        short8 af1 = *(short8*)&As[(wv * 32 + 16 + mn) * 40 + (q << 3)];
        efold0[c] = af0;
        efold1[c] = af1;
#pragma unroll
        for (int nt = 0; nt < 8; ++nt) {
            short8 bf = *(short8*)&Bs[(nt * 16 + mn) * 40 + (q << 3)];
            acc[0][nt] = __builtin_amdgcn_mfma_f32_16x16x32_bf16(af0, bf, acc[0][nt], 0, 0, 0);
            acc[1][nt] = __builtin_amdgcn_mfma_f32_16x16x32_bf16(af1, bf, acc[1][nt], 0, 0, 0);
        }
        __syncthreads();
    }
    // All As reads done (final barrier above) -> Hs alias safe.

    // ---- pre -> Hs (C-layout, own wave band; no barrier needed after) ----
#pragma unroll
    for (int h = 0; h < 2; ++h)
#pragma unroll
        for (int nt = 0; nt < 8; ++nt)
#pragma unroll
            for (int r = 0; r < 4; ++r)
                Hs[(wv * 32 + h * 16 + q * 4 + r) * 136 + nt * 16 + mn] = f2bf(acc[h][nt][r]);

    // ---- H = relu(pre + Xa[dst] + Xb[src] + b1), row-major, vector gather ----
    // lane -> row = wv*32 + (lane>>1), col half = (lane&1)*64 : own wave band.
    {
        const int row  = wv * 32 + (lane >> 1);
        const int ch   = (lane & 1) << 6;
        const unsigned short* xap = Xa + (long)dv[row] * HIDDEN + ch;
        const unsigned short* xbp = Xb + (long)sv[row] * HIDDEN + ch;
        unsigned short* hp = &Hs[row * 136 + ch];
#pragma unroll
        for (int i = 0; i < 8; ++i) {
            uint4 va = *(const uint4*)(xap + (i << 3));
            uint4 vb = *(const uint4*)(xbp + (i << 3));
            uint4 vp = *(uint4*)(hp + (i << 3));
            float fa[8], fb[8], fp[8];
            unpack8(va, fa); unpack8(vb, fb); unpack8(vp, fp);
            const float* bp = b1 + ch + (i << 3);
            uint4 nw;
            float h0 = fmaxf(fp[0] + fa[0] + fb[0] + bp[0], 0.0f);
            float h1 = fmaxf(fp[1] + fa[1] + fb[1] + bp[1], 0.0f);
            float h2 = fmaxf(fp[2] + fa[2] + fb[2] + bp[2], 0.0f);
            float h3 = fmaxf(fp[3] + fa[3] + fb[3] + bp[3], 0.0f);
            float h4 = fmaxf(fp[4] + fa[4] + fb[4] + bp[4], 0.0f);
            float h5 = fmaxf(fp[5] + fa[5] + fb[5] + bp[5], 0.0f);
            float h6 = fmaxf(fp[6] + fa[6] + fb[6] + bp[6], 0.0f);
            float h7 = fmaxf(fp[7] + fa[7] + fb[7] + bp[7], 0.0f);
            nw.x = pack2(h0, h1); nw.y = pack2(h2, h3);
            nw.z = pack2(h4, h5); nw.w = pack2(h6, h7);
            *(uint4*)(hp + (i << 3)) = nw;
        }
    }
    // No barrier: GEMM2 A-frags read only this wave's band (DS wave-ordered).

    // ---- GEMM2: H @ W2, 4 k-steps, Bs staged + prefetched ----
    f32x4 acc2[2][8];
#pragma unroll
    for (int h = 0; h < 2; ++h)
#pragma unroll
        for (int t = 0; t < 8; ++t) acc2[h][t] = (f32x4)0.0f;
    {
        const unsigned short* wp = W2T + (long)bn * 128 + bk;
        pw0 = *(const uint4*)wp;
        pw1 = *(const uint4*)(wp + 8);
    }
    for (int c = 0; c < 4; ++c) {
        *(uint4*)&Bs[bn * 40 + bk]     = pw0;
        *(uint4*)&Bs[bn * 40 + bk + 8] = pw1;
        __syncthreads();
        if (c + 1 < 4) {
            const unsigned short* wp = W2T + (long)bn * 128 + ((c + 1) << 5) + bk;
            pw0 = *(const uint4*)wp;
            pw1 = *(const uint4*)(wp + 8);
        }
        short8 af0 = *(short8*)&Hs[(wv * 32 + mn) * 136 + (c << 5) + (q << 3)];
        short8 af1 = *(short8*)&Hs[(wv * 32 + 16 + mn) * 136 + (c << 5) + (q << 3)];
#pragma unroll
        for (int nt = 0; nt < 8; ++nt) {
            short8 bf = *(short8*)&Bs[(nt * 16 + mn) * 40 + (q << 3)];
            acc2[0][nt] = __builtin_amdgcn_mfma_f32_16x16x32_bf16(af0, bf, acc2[0][nt], 0, 0, 0);
            acc2[1][nt] = __builtin_amdgcn_mfma_f32_16x16x32_bf16(af1, bf, acc2[1][nt], 0, 0, 0);
        }
        __syncthreads();
    }

    // ---- m = acc2 + b2 -> Hs (C-layout, own band) ----
#pragma unroll
    for (int h = 0; h < 2; ++h)
#pragma unroll
        for (int nt = 0; nt < 8; ++nt) {
            float b2v = b2[nt * 16 + mn];
#pragma unroll
            for (int r = 0; r < 4; ++r)
                Hs[(wv * 32 + h * 16 + q * 4 + r) * 136 + nt * 16 + mn] = f2bf(acc2[h][nt][r] + b2v);
        }

    // ---- ef_new = ef_old(regs) + m : A-frag order, 64B sectors, no re-read ----
#pragma unroll
    for (int h = 0; h < 2; ++h) {
        const int row = wv * 32 + h * 16 + mn;
        unsigned short* ep_ = ef + (eb + row) * HIDDEN + (q << 3);
#pragma unroll
        for (int c = 0; c < 4; ++c) {
            uint4 mh = *(uint4*)&Hs[row * 136 + (c << 5) + (q << 3)];
            float m[8], e[8];
            unpack8(mh, m);
            short8 eo = h ? efold1[c] : efold0[c];
            uint4 eu = *(uint4*)&eo;
            unpack8(eu, e);
            uint4 nw;
            nw.x = pack2(e[0] + m[0], e[1] + m[1]);
            nw.y = pack2(e[2] + m[2], e[3] + m[3]);
            nw.z = pack2(e[4] + m[4], e[5] + m[5]);
            nw.w = pack2(e[6] + m[6], e[7] + m[7]);
            *(uint4*)(ep_ + (c << 5)) = nw;
        }
    }

    // ---- segmented reduction by dst-run (own band rows, barrier-free) ----
    {
        const int cp = (tid & 63) << 1;
        const int qr = tid >> 6;            // == wv
        float s0 = 0.0f, s1 = 0.0f;
        int cur = dv[qr * 32];
        for (int r = 0; r < 32; ++r) {
            const int row = qr * 32 + r;
            const int d = dv[row];
            if (d != cur) {
                atomicAdd(&sums[(long)cur * HIDDEN + cp], s0);
                atomicAdd(&sums[(long)cur * HIDDEN + cp + 1], s1);
                s0 = 0.0f; s1 = 0.0f;
                cur = d;
            }
            unsigned int u = *(unsigned int*)&Hs[row * 136 + cp];
            s0 += bf2f((unsigned short)(u & 0xffff));
            s1 += bf2f((unsigned short)(u >> 16));
        }
        atomicAdd(&sums[(long)cur * HIDDEN + cp], s0);
        atomicAdd(&sums[(long)cur * HIDDEN + cp + 1], s1);
    }
}

// ---------------------------------------------------------------------------
// MFMA node layer (round-6 staged form). 64 nodes x 128 out per block.
// ---------------------------------------------------------------------------
__global__ __launch_bounds__(256, 4)
void node_layer_mfma(float* __restrict__ x,
                     float* __restrict__ sums,
                     const int* __restrict__ deg,
                     const unsigned short* __restrict__ N1T,  // [128][256] bf16
                     const float* __restrict__ b1,
                     const unsigned short* __restrict__ N2T,  // [128][128] bf16
                     const float* __restrict__ b2,
                     const unsigned short* __restrict__ W1Tn, // [128][384] next layer (or null)
                     unsigned short* __restrict__ Xa,
                     unsigned short* __restrict__ Xb)
{
    __shared__ __align__(16) unsigned short As[64 * 40];
    __shared__ __align__(16) unsigned short Bs[128 * 40];
    __shared__ __align__(16) unsigned short Hs[64 * 136];
    __shared__ float cInv[64];

    const int tid = threadIdx.x;
    const long n0 = (long)blockIdx.x * 64;
    if (tid < 64) {
        long n = n0 + tid;
        cInv[tid] = (n < NNODES) ? 1.0f / fmaxf((float)deg[n], 1.0f) : 0.0f;
    }

    const int lane = tid & 63;
    const int wv   = tid >> 6;
    const int mn   = lane & 15;
    const int q    = lane >> 4;
    const int srow = tid >> 2;
    const int sseg = tid & 3;
    const int bn   = tid >> 1;
    const int bk   = (tid & 1) << 4;

    long nr = n0 + srow;
    if (nr >= NNODES) nr = NNODES - 1;

    __syncthreads();

    f32x4 acc[8];
#pragma unroll
    for (int t = 0; t < 8; ++t) acc[t] = (f32x4)0.0f;

    float4 pa0, pa1;
    uint4 pb0, pb1;
    {
        const float* spx = x + nr * HIDDEN + (sseg << 3);
        pa0 = *(const float4*)spx;
        pa1 = *(const float4*)(spx + 4);
        const unsigned short* wp = N1T + (long)bn * 256 + bk;
        pb0 = *(const uint4*)wp;
        pb1 = *(const uint4*)(wp + 8);
    }
    float scCur = 1.0f;
    for (int c = 0; c < 8; ++c) {
        {
            uint4 w;
            w.x = pack2(pa0.x * scCur, pa0.y * scCur); w.y = pack2(pa0.z * scCur, pa0.w * scCur);
            w.z = pack2(pa1.x * scCur, pa1.y * scCur); w.w = pack2(pa1.z * scCur, pa1.w * scCur);
            *(uint4*)&As[srow * 40 + (sseg << 3)] = w;
        }
        *(uint4*)&Bs[bn * 40 + bk]     = pb0;
        *(uint4*)&Bs[bn * 40 + bk + 8] = pb1;
        __syncthreads();
        if (c + 1 < 8) {
            const int cn = c + 1;
            const float* base = (cn < 4) ? x : sums;
            scCur = (cn < 4) ? 1.0f : cInv[srow];
            const float* spx = base + nr * HIDDEN + ((cn & 3) << 5) + (sseg << 3);
            pa0 = *(const float4*)spx;
            pa1 = *(const float4*)(spx + 4);
            const unsigned short* wp = N1T + (long)bn * 256 + (cn << 5) + bk;
            pb0 = *(const uint4*)wp;
            pb1 = *(const uint4*)(wp + 8);
        }
        short8 af = *(short8*)&As[(wv * 16 + mn) * 40 + (q << 3)];
#pragma unroll
        for (int nt = 0; nt < 8; ++nt) {
            short8 bf = *(short8*)&Bs[(nt * 16 + mn) * 40 + (q << 3)];
            acc[nt] = __builtin_amdgcn_mfma_f32_16x16x32_bf16(af, bf, acc[nt], 0, 0, 0);
        }
        __syncthreads();
    }

    // zero own sums rows for the next layer
    {
        long row = n0 + srow;
        if (row < NNODES) {
            float4 z = make_float4(0.f, 0.f, 0.f, 0.f);
            float* p = sums + row * HIDDEN + (sseg << 5);
#pragma unroll
            for (int i = 0; i < 8; ++i) ((float4*)p)[i] = z;
        }
    }

#pragma unroll
    for (int nt = 0; nt < 8; ++nt) {
        float b1v = b1[nt * 16 + mn];
#pragma unroll
        for (int r = 0; r < 4; ++r) {
            float hv = fmaxf(acc[nt][r] + b1v, 0.0f);
            Hs[(wv * 16 + q * 4 + r) * 136 + nt * 16 + mn] = f2bf(hv);
        }
    }

    f32x4 acc2[8];
#pragma unroll
    for (int t = 0; t < 8; ++t) acc2[t] = (f32x4)0.0f;
    {
        const unsigned short* wp = N2T + (long)bn * 128 + bk;
        pb0 = *(const uint4*)wp;
        pb1 = *(const uint4*)(wp + 8);
    }
    for (int c = 0; c < 4; ++c) {
        *(uint4*)&Bs[bn * 40 + bk]     = pb0;
        *(uint4*)&Bs[bn * 40 + bk + 8] = pb1;
        __syncthreads();
        if (c + 1 < 4) {
            const unsigned short* wp = N2T + (long)bn * 128 + ((c + 1) << 5) + bk;
            pb0 = *(const uint4*)wp;
            pb1 = *(const uint4*)(wp + 8);
        }
        short8 af = *(short8*)&Hs[(wv * 16 + mn) * 136 + (c << 5) + (q << 3)];
#pragma unroll
        for (int nt = 0; nt < 8; ++nt) {
            short8 bf = *(short8*)&Bs[(nt * 16 + mn) * 40 + (q << 3)];
            acc2[nt] = __builtin_amdgcn_mfma_f32_16x16x32_bf16(af, bf, acc2[nt], 0, 0, 0);
        }
        __syncthreads();
    }

    // ---- xnew = x + acc2 + b2 (exact fp32); stage xnew bf16 into Hs ----
#pragma unroll
    for (int nt = 0; nt < 8; ++nt) {
        float b2v = b2[nt * 16 + mn];
#pragma unroll
        for (int r = 0; r < 4; ++r) {
            long row = n0 + wv * 16 + q * 4 + r;
            float xn = 0.0f;
            if (row < NNODES) {
                float* p = x + row * HIDDEN + nt * 16 + mn;
                xn = *p + acc2[nt][r] + b2v;
                *p = xn;
            }
            Hs[(wv * 16 + q * 4 + r) * 136 + nt * 16 + mn] = f2bf(xn);
        }
    }

    // ---- Xa/Xb for next layer: xnew @ W1a / W1b ----
    if (W1Tn) {
#pragma unroll
        for (int half = 0; half < 2; ++half) {
            f32x4 accN[8];
#pragma unroll
            for (int t = 0; t < 8; ++t) accN[t] = (f32x4)0.0f;
            const int kbase = half << 7;
            {
                const unsigned short* wp = W1Tn + (long)bn * 384 + kbase + bk;
                pb0 = *(const uint4*)wp;
                pb1 = *(const uint4*)(wp + 8);
            }
            for (int c = 0; c < 4; ++c) {
                *(uint4*)&Bs[bn * 40 + bk]     = pb0;
                *(uint4*)&Bs[bn * 40 + bk + 8] = pb1;
                __syncthreads();
                if (c + 1 < 4) {
                    const unsigned short* wp = W1Tn + (long)bn * 384 + kbase + ((c + 1) << 5) + bk;
                    pb0 = *(const uint4*)wp;
                    pb1 = *(const uint4*)(wp + 8);
                }
                short8 af = *(short8*)&Hs[(wv * 16 + mn) * 136 + (c << 5) + (q << 3)];
#pragma unroll
                for (int nt = 0; nt < 8; ++nt) {
                    short8 bf = *(short8*)&Bs[(nt * 16 + mn) * 40 + (q << 3)];
                    accN[nt] = __builtin_amdgcn_mfma_f32_16x16x32_bf16(af, bf, accN[nt], 0, 0, 0);
                }
                __syncthreads();
            }
            unsigned short* Xout = half ? Xb : Xa;
#pragma unroll
            for (int nt = 0; nt < 8; ++nt) {
#pragma unroll
                for (int r = 0; r < 4; ++r) {
                    long row = n0 + wv * 16 + q * 4 + r;
                    if (row < NNODES) {
                        Xout[row * HIDDEN + nt * 16 + mn] = f2bf(accN[nt][r]);
                    }
                }
            }
        }
    }
}

// ---------------------------------------------------------------------------
// Decoder + row L2-normalize (one wave per node)
// ---------------------------------------------------------------------------
__global__ void decode_kernel(const float* __restrict__ x,
                              const float* __restrict__ w,
                              const float* __restrict__ b,
                              float* __restrict__ out)
{
    int gid = blockIdx.x * blockDim.x + threadIdx.x;
    int node = gid >> 6;
    int lane = threadIdx.x & 63;
    if (node >= NNODES) return;
    float a0 = 0.f, a1 = 0.f, a2 = 0.f;
#pragma unroll
    for (int k = lane; k < HIDDEN; k += 64) {
        float xv = x[(long)node * HIDDEN + k];
        a0 = fmaf(xv, w[k * 3 + 0], a0);
        a1 = fmaf(xv, w[k * 3 + 1], a1);
        a2 = fmaf(xv, w[k * 3 + 2], a2);
    }
#pragma unroll
    for (int off = 32; off > 0; off >>= 1) {
        a0 += __shfl_down(a0, off);
        a1 += __shfl_down(a1, off);
        a2 += __shfl_down(a2, off);
    }
    if (lane == 0) {
        a0 += b[0]; a1 += b[1]; a2 += b[2];
        float nrm = sqrtf(a0 * a0 + a1 * a1 + a2 * a2);
        float inv = 1.0f / fmaxf(nrm, 1e-12f);
        out[(long)node * 3 + 0] = a0 * inv;
        out[(long)node * 3 + 1] = a1 * inv;
        out[(long)node * 3 + 2] = a2 * inv;
    }
}

// ---------------------------------------------------------------------------
extern "C" void kernel_launch(void* const* d_in, const int* in_sizes, int n_in,
                              void* d_out, int out_size, void* d_ws, size_t ws_size,
                              hipStream_t stream)
{
    const float* edge_attr = (const float*)d_in[1];
    const int*   ei        = (const int*)d_in[2];
    const float* enc_w     = (const float*)d_in[3];
    const float* enc_b     = (const float*)d_in[4];
    const float* dec_w     = (const float*)d_in[5];
    const float* dec_b     = (const float*)d_in[6];
    const float* edge_w1   = (const float*)d_in[7];
    const float* edge_b1   = (const float*)d_in[8];
    const float* edge_w2   = (const float*)d_in[9];
    const float* edge_b2   = (const float*)d_in[10];
    const float* node_w1   = (const float*)d_in[11];
    const float* node_b1   = (const float*)d_in[12];
    const float* node_w2   = (const float*)d_in[13];
    const float* node_b2   = (const float*)d_in[14];

    // workspace layout (bytes), 16B-aligned, total ~255.4 MB
    char* ws = (char*)d_ws;
    unsigned short* ef  = (unsigned short*)(ws);                  // 163,840,000
    float* x      = (float*)(ws + 163840000L);                    //  25,600,000
    float* sums   = (float*)(ws + 189440000L);                    //  25,600,000
    int*   src32  = (int*)  (ws + 215040000L);                    //   2,560,000
    int*   dst32  = (int*)  (ws + 217600000L);                    //   2,560,000
    int*   sp     = (int*)  (ws + 220160000L);                    //   2,560,000
    int*   dp     = (int*)  (ws + 222720000L);                    //   2,560,000
    int*   eperm  = (int*)  (ws + 225280000L);                    //   2,560,000
    int*   deg    = (int*)  (ws + 227840000L);                    //     200,704
    int*   off    = (int*)  (ws + 228040704L);                    //     200,704
    int*   cursor = (int*)  (ws + 228241408L);                    //     200,704
    int*   flag   = (int*)  (ws + 228442112L);                    //          64
    unsigned short* W1T = (unsigned short*)(ws + 228442176L);     //     589,824
    unsigned short* W2T = (unsigned short*)(ws + 229032000L);     //     196,608
    unsigned short* N1T = (unsigned short*)(ws + 229228608L);     //     393,216
    unsigned short* N2T = (unsigned short*)(ws + 229621824L);     //     196,608
    unsigned short* Xa  = (unsigned short*)(ws + 229818432L);     //  12,800,000
    unsigned short* Xb  = (unsigned short*)(ws + 242618432L);     //  12,800,000
    // end: 255,418,432

    float* out = (float*)d_out;

    hipMemsetAsync(x, 0, (size_t)NNODES * HIDDEN * sizeof(float), stream);
    hipMemsetAsync(sums, 0, (size_t)NNODES * HIDDEN * sizeof(float), stream);
    hipMemsetAsync(deg, 0, 200704, stream);
    hipMemsetAsync(Xa, 0, 25600000, stream);   // Xa + Xb (contiguous)

    detect_kernel<<<1, 64, 0, stream>>>(ei, flag);
    normidx_kernel<<<(NEDGES + 255) / 256, 256, 0, stream>>>(ei, flag, src32, dst32);
    degree_kernel<<<(NEDGES + 255) / 256, 256, 0, stream>>>(dst32, deg);
    scan_kernel<<<1, SCAN_T, 0, stream>>>(deg, off, cursor);
    scatter_kernel<<<(NEDGES + 255) / 256, 256, 0, stream>>>(src32, dst32, cursor, sp, dp, eperm);
    encode_kernel<<<(NEDGES * 32 + 255) / 256, 256, 0, stream>>>(edge_attr, enc_w, enc_b, eperm, ef);

    transpose_kernel<<<(6 * 384 * 128 + 255) / 256, 256, 0, stream>>>(edge_w1, W1T, 384, 128, 6);
    transpose_kernel<<<(6 * 128 * 128 + 255) / 256, 256, 0, stream>>>(edge_w2, W2T, 128, 128, 6);
    transpose_kernel<<<(6 * 256 * 128 + 255) / 256, 256, 0, stream>>>(node_w1, N1T, 256, 128, 6);
    transpose_kernel<<<(6 * 128 * 128 + 255) / 256, 256, 0, stream>>>(node_w2, N2T, 128, 128, 6);

    for (int l = 0; l < NLAYERS; ++l) {
        edge_layer_mfma<<<NEDGES / 128, 256, 0, stream>>>(
            Xa, Xb, ef, sums, sp, dp,
            W1T + (long)l * 384 * 128, edge_b1 + (long)l * HIDDEN,
            W2T + (long)l * 128 * 128, edge_b2 + (long)l * HIDDEN);
        const unsigned short* w1next = (l + 1 < NLAYERS) ? (W1T + (long)(l + 1) * 384 * 128) : nullptr;
        node_layer_mfma<<<(NNODES + 63) / 64, 256, 0, stream>>>(
            x, sums, deg,
            N1T + (long)l * 256 * 128, node_b1 + (long)l * HIDDEN,
            N2T + (long)l * 128 * 128, node_b2 + (long)l * HIDDEN,
            w1next, Xa, Xb);
    }

    decode_kernel<<<(NNODES * 64 + 255) / 256, 256, 0, stream>>>(x, dec_w, dec_b, out);
}